// Round 1
// baseline (4875.699 us; speedup 1.0000x reference)
//
#include <hip/hip_runtime.h>

typedef unsigned int u32;
typedef unsigned short u16;
typedef _Float16 f16;
typedef f16 f16x2 __attribute__((ext_vector_type(2)));

__device__ __forceinline__ float fdot2(u32 a, u32 b, float c) {
#if __has_builtin(__builtin_amdgcn_fdot2)
    return __builtin_amdgcn_fdot2(__builtin_bit_cast(f16x2, a),
                                  __builtin_bit_cast(f16x2, b), c, false);
#else
    f16x2 av = __builtin_bit_cast(f16x2, a), bv = __builtin_bit_cast(f16x2, b);
    c += (float)av[0] * (float)bv[0];
    c += (float)av[1] * (float)bv[1];
    return c;
#endif
}

__device__ __forceinline__ u32 pack2h(float a, float b) {
    f16x2 h; h[0] = (f16)a; h[1] = (f16)b;
    return __builtin_bit_cast(u32, h);
}
__device__ __forceinline__ float h2f(u16 x) { return (float)__builtin_bit_cast(f16, x); }
__device__ __forceinline__ u16 f2h(float x) { f16 h = (f16)x; return __builtin_bit_cast(u16, h); }

__device__ __forceinline__ float fexp(float x) {
#if __has_builtin(__builtin_amdgcn_exp2f)
    return __builtin_amdgcn_exp2f(x * 1.44269504088896f);
#else
    return __expf(x);
#endif
}
__device__ __forceinline__ float frcp(float x) {
#if __has_builtin(__builtin_amdgcn_rcpf)
    return __builtin_amdgcn_rcpf(x);
#else
    return 1.0f / x;
#endif
}
__device__ __forceinline__ float fsigmoid(float x) { return frcp(1.0f + fexp(-x)); }
__device__ __forceinline__ float ftanh_pos(float x) { return 1.0f - 2.0f * frcp(fexp(2.0f * x) + 1.0f); }

// ---------------------------------------------------------------------------
// K0: pack Wi and Wy into f16-pair arrays, layout [k_pair][d] (coalesced for K2)
//   Wpk [p][d] = (Wi[d][2p], Wi[d][2p+1])   p<256, d<512
//   Wypk[p][o] = (Wy[o][2p], Wy[o][2p+1])
// ---------------------------------------------------------------------------
__global__ __launch_bounds__(512) void k0_pack(const float* __restrict__ Wi,
                                               const float* __restrict__ Wy,
                                               u32* __restrict__ Wpk,
                                               u32* __restrict__ Wypk) {
    const int p = blockIdx.x & 255;
    const int d = threadIdx.x;
    const float* src = (blockIdx.x < 256) ? Wi : Wy;
    u32* dst = (blockIdx.x < 256) ? Wpk : Wypk;
    float v0 = src[(size_t)d * 512 + 2 * p];
    float v1 = src[(size_t)d * 512 + 2 * p + 1];
    dst[(size_t)p * 512 + d] = pack2h(v0, v1);
}

// ---------------------------------------------------------------------------
// K1: gate pre-activations (parallel over all t):
//   Xi[t,b,d] = x@Wi.T + 2*bi ; Xz = x@Wz.T + bz+bi ; Xo = x@Wo.T + bo+bi
// stored as f16. WG: 2 timesteps x 128-d-slice x all 3 gates. dot2-f16 compute.
// ---------------------------------------------------------------------------
__global__ __launch_bounds__(256) void k1_gates(
    const float* __restrict__ word,
    const float* __restrict__ Wi, const float* __restrict__ Wz, const float* __restrict__ Wo,
    const float* __restrict__ bi, const float* __restrict__ bz, const float* __restrict__ bo,
    u16* __restrict__ Xi, u16* __restrict__ Xz, u16* __restrict__ Xo)
{
    __shared__ u32 ws2[3][32][132];   // [gate][k-pair][d_l(128) padded to 132]
    __shared__ u32 xs2[2][32][36];    // [t-sub][k-pair][b(32) padded to 36]

    const int tid = threadIdx.x;
    const int d_l = tid & 63;          // lane
    const int bq  = tid >> 6;          // wave id 0..3 -> b block of 8
    const int t0  = blockIdx.x * 2;
    const int d0  = blockIdx.y * 128;

    const float* Wg[3] = {Wi, Wz, Wo};

    float acc[2][2][8][3];             // [tt][dblk][b][gate]
    #pragma unroll
    for (int tt = 0; tt < 2; ++tt)
        #pragma unroll
        for (int db = 0; db < 2; ++db)
            #pragma unroll
            for (int j = 0; j < 8; ++j)
                #pragma unroll
                for (int g = 0; g < 3; ++g) acc[tt][db][j][g] = 0.0f;

    for (int k0 = 0; k0 < 512; k0 += 64) {
        // stage x (f32 -> f16 pairs), layout [p][b]
        {
            const int p = tid & 31, bg = tid >> 5;   // p k-pair, bg 0..7
            #pragma unroll
            for (int tt = 0; tt < 2; ++tt)
                #pragma unroll
                for (int j = 0; j < 4; ++j) {
                    int b = bg * 4 + j;
                    const float2 v = *(const float2*)(word + (((size_t)(t0 + tt) * 32 + b) * 512 + k0 + 2 * p));
                    xs2[tt][p][b] = pack2h(v.x, v.y);
                }
        }
        // stage W tiles (f32 -> f16 pairs), layout [g][p][d_l]
        {
            const int q = tid & 15, r = tid >> 4;    // q k-quad, r row group
            #pragma unroll
            for (int g = 0; g < 3; ++g)
                #pragma unroll
                for (int s = 0; s < 8; ++s) {
                    int i = r + 16 * s;  // 0..127
                    const float4 v = *(const float4*)(Wg[g] + ((size_t)(d0 + i) * 512 + k0 + 4 * q));
                    ws2[g][2 * q + 0][i] = pack2h(v.x, v.y);
                    ws2[g][2 * q + 1][i] = pack2h(v.z, v.w);
                }
        }
        __syncthreads();
        // compute: per k-pair, 96 dot2 per thread
        #pragma unroll 2
        for (int p = 0; p < 32; ++p) {
            u32 x2[2][8];
            #pragma unroll
            for (int tt = 0; tt < 2; ++tt) {
                const uint4* xr = (const uint4*)&xs2[tt][p][bq * 8];  // broadcast (wave-uniform)
                uint4 xa = xr[0], xb = xr[1];
                x2[tt][0] = xa.x; x2[tt][1] = xa.y; x2[tt][2] = xa.z; x2[tt][3] = xa.w;
                x2[tt][4] = xb.x; x2[tt][5] = xb.y; x2[tt][6] = xb.z; x2[tt][7] = xb.w;
            }
            u32 w2[3][2];
            #pragma unroll
            for (int g = 0; g < 3; ++g) {
                w2[g][0] = ws2[g][p][d_l];
                w2[g][1] = ws2[g][p][d_l + 64];
            }
            #pragma unroll
            for (int tt = 0; tt < 2; ++tt)
                #pragma unroll
                for (int db = 0; db < 2; ++db)
                    #pragma unroll
                    for (int j = 0; j < 8; ++j)
                        #pragma unroll
                        for (int g = 0; g < 3; ++g)
                            acc[tt][db][j][g] = fdot2(x2[tt][j], w2[g][db], acc[tt][db][j][g]);
        }
        __syncthreads();
    }

    // epilogue: add biases, store f16
    #pragma unroll
    for (int db = 0; db < 2; ++db) {
        const int d = d0 + 64 * db + d_l;
        const float b0 = 2.0f * bi[d];
        const float b1 = bz[d] + bi[d];
        const float b2 = bo[d] + bi[d];
        #pragma unroll
        for (int tt = 0; tt < 2; ++tt)
            #pragma unroll
            for (int j = 0; j < 8; ++j) {
                const size_t o = ((size_t)(t0 + tt) * 32 + (bq * 8 + j)) * 512 + d;
                Xi[o] = f2h(acc[tt][db][j][0] + b0);
                Xz[o] = f2h(acc[tt][db][j][1] + b1);
                Xo[o] = f2h(acc[tt][db][j][2] + b2);
            }
    }
}

// ---------------------------------------------------------------------------
// K2: sequential recurrence, one WG per batch element (b = blockIdx.x).
// Wi fully resident: 228 f16-pairs/thread in VGPRs + 28 pairs in LDS.
// h ping-pong in LDS (f16). Per step: v[d]=h.Wi[d,:], gates, h update.
// Epilogue: out[b,:] = h_final @ Wy.T + by (Wy streamed once).
// ---------------------------------------------------------------------------
__global__ __launch_bounds__(512, 2) void k2_recur(
    const u16* __restrict__ Xi, const u16* __restrict__ Xz, const u16* __restrict__ Xo,
    const u32* __restrict__ Wpk, const u32* __restrict__ Wypk,
    const float* __restrict__ by, float* __restrict__ out)
{
    __shared__ u32 wlds[28][512];                 // tail weight pairs 228..255
    __shared__ alignas(16) u16 hbuf[2][512];      // h ping-pong, f16

    const int b = blockIdx.x;
    const int tid = threadIdx.x;                  // = output dim d

    // resident weights: pairs 0..227 in VGPRs
    u32 w[228];
    #pragma unroll
    for (int p = 0; p < 228; ++p) w[p] = Wpk[(size_t)p * 512 + tid];
    // tail pairs 228..255 in LDS
    #pragma unroll
    for (int j = 0; j < 28; ++j) wlds[j][tid] = Wpk[(size_t)(228 + j) * 512 + tid];

    hbuf[0][tid] = (u16)0;   // h = 0 at t = 0
    __syncthreads();

    // prefetch X for t=0
    size_t idx0 = ((size_t)0 * 32 + b) * 512 + tid;
    u16 xi_c = Xi[idx0], xz_c = Xz[idx0], xo_c = Xo[idx0];

    for (int t = 0; t < 2048; ++t) {
        const int cur = t & 1, nxt = cur ^ 1;
        // prefetch next step's X (wraps harmlessly at t=2047)
        const int tn = (t + 1) & 2047;
        const size_t idxn = ((size_t)tn * 32 + b) * 512 + tid;
        u16 xi_n = Xi[idxn], xz_n = Xz[idxn], xo_n = Xo[idxn];

        const uint4* hv = (const uint4*)&hbuf[cur][0];
        float a0 = 0.f, a1 = 0.f, a2 = 0.f, a3 = 0.f;
        #pragma unroll
        for (int j = 0; j < 57; ++j) {            // pairs 0..227 from VGPRs
            uint4 hc = hv[j];                      // broadcast ds_read_b128
            a0 = fdot2(hc.x, w[4 * j + 0], a0);
            a1 = fdot2(hc.y, w[4 * j + 1], a1);
            a2 = fdot2(hc.z, w[4 * j + 2], a2);
            a3 = fdot2(hc.w, w[4 * j + 3], a3);
        }
        #pragma unroll
        for (int j = 57; j < 64; ++j) {           // pairs 228..255 from LDS
            uint4 hc = hv[j];
            const int q = 4 * (j - 57);
            a0 = fdot2(hc.x, wlds[q + 0][tid], a0);
            a1 = fdot2(hc.y, wlds[q + 1][tid], a1);
            a2 = fdot2(hc.z, wlds[q + 2][tid], a2);
            a3 = fdot2(hc.w, wlds[q + 3][tid], a3);
        }
        const float v = (a0 + a1) + (a2 + a3);

        const float zi = fsigmoid(h2f(xi_c) + v);
        const float z  = fsigmoid(h2f(xz_c) + v);
        const float zo = fsigmoid(h2f(xo_c) + v);
        const float hn = zo * ftanh_pos(zi * z);

        hbuf[nxt][tid] = f2h(hn);
        __syncthreads();

        xi_c = xi_n; xz_c = xz_n; xo_c = xo_n;
    }

    // epilogue: final h is in hbuf[0] (t=2047 wrote nxt=0). out = h @ Wy.T + by
    {
        const uint4* hv = (const uint4*)&hbuf[0][0];
        float a0 = 0.f, a1 = 0.f, a2 = 0.f, a3 = 0.f;
        #pragma unroll
        for (int j = 0; j < 64; ++j) {
            uint4 hc = hv[j];
            a0 = fdot2(hc.x, Wypk[(size_t)(4 * j + 0) * 512 + tid], a0);
            a1 = fdot2(hc.y, Wypk[(size_t)(4 * j + 1) * 512 + tid], a1);
            a2 = fdot2(hc.z, Wypk[(size_t)(4 * j + 2) * 512 + tid], a2);
            a3 = fdot2(hc.w, Wypk[(size_t)(4 * j + 3) * 512 + tid], a3);
        }
        out[(size_t)b * 512 + tid] = (a0 + a1) + (a2 + a3) + by[tid];
    }
}

// ---------------------------------------------------------------------------
extern "C" void kernel_launch(void* const* d_in, const int* in_sizes, int n_in,
                              void* d_out, int out_size, void* d_ws, size_t ws_size,
                              hipStream_t stream) {
    const float* word = (const float*)d_in[0];
    // d_in[1]=Wf, d_in[2]=bf : dead in the reference (c==0 path), unused.
    const float* Wi = (const float*)d_in[3];
    const float* bi = (const float*)d_in[4];
    const float* Wz = (const float*)d_in[5];
    const float* bz = (const float*)d_in[6];
    const float* Wo = (const float*)d_in[7];
    const float* bo = (const float*)d_in[8];
    const float* Wy = (const float*)d_in[9];
    const float* by = (const float*)d_in[10];
    float* out = (float*)d_out;

    char* ws = (char*)d_ws;
    const size_t XN = (size_t)2048 * 32 * 512 * sizeof(u16);  // 64 MB per gate array
    u16* Xi = (u16*)(ws);
    u16* Xz = (u16*)(ws + XN);
    u16* Xo = (u16*)(ws + 2 * XN);
    u32* Wpk  = (u32*)(ws + 3 * XN);                 // 512 KB
    u32* Wypk = (u32*)(ws + 3 * XN + (size_t)524288);

    k0_pack<<<512, 512, 0, stream>>>(Wi, Wy, Wpk, Wypk);

    dim3 g1(1024, 4);
    k1_gates<<<g1, 256, 0, stream>>>(word, Wi, Wz, Wo, bi, bz, bo, Xi, Xz, Xo);

    k2_recur<<<32, 512, 0, stream>>>(Xi, Xz, Xo, Wpk, Wypk, by, out);
}

// Round 2
// 4811.428 us; speedup vs baseline: 1.0134x; 1.0134x over previous
//
#include <hip/hip_runtime.h>

typedef unsigned int u32;
typedef unsigned short u16;
typedef _Float16 f16;
typedef f16 f16x2 __attribute__((ext_vector_type(2)));

__device__ __forceinline__ float fdot2(u32 a, u32 b, float c) {
#if __has_builtin(__builtin_amdgcn_fdot2)
    return __builtin_amdgcn_fdot2(__builtin_bit_cast(f16x2, a),
                                  __builtin_bit_cast(f16x2, b), c, false);
#else
    f16x2 av = __builtin_bit_cast(f16x2, a), bv = __builtin_bit_cast(f16x2, b);
    c += (float)av[0] * (float)bv[0];
    c += (float)av[1] * (float)bv[1];
    return c;
#endif
}

__device__ __forceinline__ u32 pack2h(float a, float b) {
    f16x2 h; h[0] = (f16)a; h[1] = (f16)b;
    return __builtin_bit_cast(u32, h);
}
__device__ __forceinline__ float h2f(u16 x) { return (float)__builtin_bit_cast(f16, x); }
__device__ __forceinline__ u16 f2h(float x) { f16 h = (f16)x; return __builtin_bit_cast(u16, h); }

__device__ __forceinline__ float fexp(float x) {
#if __has_builtin(__builtin_amdgcn_exp2f)
    return __builtin_amdgcn_exp2f(x * 1.44269504088896f);
#else
    return __expf(x);
#endif
}
__device__ __forceinline__ float frcp(float x) {
#if __has_builtin(__builtin_amdgcn_rcpf)
    return __builtin_amdgcn_rcpf(x);
#else
    return 1.0f / x;
#endif
}
__device__ __forceinline__ float fsigmoid(float x) { return frcp(1.0f + fexp(-x)); }
__device__ __forceinline__ float ftanh_pos(float x) { return 1.0f - 2.0f * frcp(fexp(2.0f * x) + 1.0f); }

// DPP quad-perm butterfly add: x += lane(x ^ mask) within each quad.
// 0xB1 = quad_perm [1,0,3,2] (xor 1); 0x4E = quad_perm [2,3,0,1] (xor 2).
template <int CTRL>
__device__ __forceinline__ float dpp_xor_add(float x) {
    int y = __builtin_amdgcn_update_dpp(0, __builtin_bit_cast(int, x), CTRL, 0xF, 0xF, true);
    return x + __builtin_bit_cast(float, y);
}

// ---------------------------------------------------------------------------
// K0: pack weights to f16 pairs.
//   WpkT[d][p] = (Wi[d][2p], Wi[d][2p+1])   d<512, p<256   (row-major rows)
//   Wypk[p][d] = (Wy[d][2p], Wy[d][2p+1])   (K2 epilogue layout)
// ---------------------------------------------------------------------------
__global__ __launch_bounds__(256) void k0_pack(const float* __restrict__ Wi,
                                               const float* __restrict__ Wy,
                                               u32* __restrict__ WpkT,
                                               u32* __restrict__ Wypk) {
    const int bx = blockIdx.x, tid = threadIdx.x;
    if (bx < 512) {
        const float2 v = *(const float2*)(Wi + (size_t)bx * 512 + 2 * tid);
        WpkT[(size_t)bx * 256 + tid] = pack2h(v.x, v.y);
    } else {
        const int p = bx - 512;  // 0..255
        #pragma unroll
        for (int r = 0; r < 2; ++r) {
            const int d = tid + 256 * r;
            Wypk[(size_t)p * 512 + d] =
                pack2h(Wy[(size_t)d * 512 + 2 * p], Wy[(size_t)d * 512 + 2 * p + 1]);
        }
    }
}

// ---------------------------------------------------------------------------
// K1: gate pre-activations (parallel over all t):
//   Xi = x@Wi.T + 2*bi ; Xz = x@Wz.T + bz+bi ; Xo = x@Wo.T + bo+bi   (f16 out)
// K-chunk 32 (LDS 30KB) -> 2 WGs/CU for latency hiding.
// ---------------------------------------------------------------------------
__global__ __launch_bounds__(256) void k1_gates(
    const float* __restrict__ word,
    const float* __restrict__ Wi, const float* __restrict__ Wz, const float* __restrict__ Wo,
    const float* __restrict__ bi, const float* __restrict__ bz, const float* __restrict__ bo,
    u16* __restrict__ Xi, u16* __restrict__ Xz, u16* __restrict__ Xo)
{
    __shared__ u32 ws2[3][16][132];   // [gate][k-pair][d_l(128) pad 132]
    __shared__ u32 xs2[2][16][36];    // [t-sub][k-pair][b(32) pad 36]

    const int tid = threadIdx.x;
    const int d_l = tid & 63;
    const int bq  = tid >> 6;
    const int t0  = blockIdx.x * 2;
    const int d0  = blockIdx.y * 128;

    const float* Wg[3] = {Wi, Wz, Wo};

    float acc[2][2][8][3];
    #pragma unroll
    for (int tt = 0; tt < 2; ++tt)
        #pragma unroll
        for (int db = 0; db < 2; ++db)
            #pragma unroll
            for (int j = 0; j < 8; ++j)
                #pragma unroll
                for (int g = 0; g < 3; ++g) acc[tt][db][j][g] = 0.0f;

    for (int k0 = 0; k0 < 512; k0 += 32) {
        // stage x: 2t x 16p x 32b
        {
            const int p = tid & 15, bg = tid >> 4;   // bg 0..15
            #pragma unroll
            for (int tt = 0; tt < 2; ++tt)
                #pragma unroll
                for (int j = 0; j < 2; ++j) {
                    const int bb = bg * 2 + j;
                    const float2 v = *(const float2*)(word + (((size_t)(t0 + tt) * 32 + bb) * 512 + k0 + 2 * p));
                    xs2[tt][p][bb] = pack2h(v.x, v.y);
                }
        }
        // stage W tiles: 3g x 16p x 128i
        {
            const int q = tid & 7, r = tid >> 3;     // q f32-quad 0..7, r 0..31
            #pragma unroll
            for (int g = 0; g < 3; ++g)
                #pragma unroll
                for (int s = 0; s < 4; ++s) {
                    const int i = r + 32 * s;
                    const float4 v = *(const float4*)(Wg[g] + ((size_t)(d0 + i) * 512 + k0 + 4 * q));
                    ws2[g][2 * q + 0][i] = pack2h(v.x, v.y);
                    ws2[g][2 * q + 1][i] = pack2h(v.z, v.w);
                }
        }
        __syncthreads();
        #pragma unroll 2
        for (int p = 0; p < 16; ++p) {
            u32 x2[2][8];
            #pragma unroll
            for (int tt = 0; tt < 2; ++tt) {
                const uint4* xr = (const uint4*)&xs2[tt][p][bq * 8];
                uint4 xa = xr[0], xb = xr[1];
                x2[tt][0] = xa.x; x2[tt][1] = xa.y; x2[tt][2] = xa.z; x2[tt][3] = xa.w;
                x2[tt][4] = xb.x; x2[tt][5] = xb.y; x2[tt][6] = xb.z; x2[tt][7] = xb.w;
            }
            u32 w2[3][2];
            #pragma unroll
            for (int g = 0; g < 3; ++g) {
                w2[g][0] = ws2[g][p][d_l];
                w2[g][1] = ws2[g][p][d_l + 64];
            }
            #pragma unroll
            for (int tt = 0; tt < 2; ++tt)
                #pragma unroll
                for (int db = 0; db < 2; ++db)
                    #pragma unroll
                    for (int j = 0; j < 8; ++j)
                        #pragma unroll
                        for (int g = 0; g < 3; ++g)
                            acc[tt][db][j][g] = fdot2(x2[tt][j], w2[g][db], acc[tt][db][j][g]);
        }
        __syncthreads();
    }

    #pragma unroll
    for (int db = 0; db < 2; ++db) {
        const int d = d0 + 64 * db + d_l;
        const float b0 = 2.0f * bi[d];
        const float b1 = bz[d] + bi[d];
        const float b2 = bo[d] + bi[d];
        #pragma unroll
        for (int tt = 0; tt < 2; ++tt)
            #pragma unroll
            for (int j = 0; j < 8; ++j) {
                const size_t o = ((size_t)(t0 + tt) * 32 + (bq * 8 + j)) * 512 + d;
                Xi[o] = f2h(acc[tt][db][j][0] + b0);
                Xz[o] = f2h(acc[tt][db][j][1] + b1);
                Xo[o] = f2h(acc[tt][db][j][2] + b2);
            }
    }
}

// ---------------------------------------------------------------------------
// K2: sequential recurrence, one WG (512 thr) per batch element.
// K-split 4: thread tid=(dg=tid>>2, kq=tid&3) computes 4 outputs d=4dg+j over
// K-quarter kq. Weights: 57 pairs/output in VGPRs (228 regs) + 7 pairs/output
// in LDS. h reads: 16 uint4/step (vs 64 unsplit). Quad DPP butterfly reduces
// partials; thread tid finalizes d=tid (j==kq). One barrier per step.
// ---------------------------------------------------------------------------
__global__ __launch_bounds__(512, 2) void k2_recur(
    const u16* __restrict__ Xi, const u16* __restrict__ Xz, const u16* __restrict__ Xo,
    const u32* __restrict__ WpkT, const u32* __restrict__ Wypk,
    const float* __restrict__ by, float* __restrict__ out)
{
    __shared__ alignas(16) u32 wlds[7][2048];     // [slot s][tid*4 + j]  (pairs p=57+s)
    __shared__ alignas(16) u16 hbuf[2][512];      // h ping-pong, f16

    const int b = blockIdx.x;
    const int tid = threadIdx.x;
    const int kq = tid & 3, dg = tid >> 2;

    // load weights: w[j][p] = Wi[4dg+j][pair 64kq+p]; p=0..56 VGPR, 57..63 LDS
    u32 w[4][57];
    #pragma unroll
    for (int j = 0; j < 4; ++j) {
        const u32* row = WpkT + (size_t)(4 * dg + j) * 256 + 64 * kq;
        const uint4* rv = (const uint4*)row;
        #pragma unroll
        for (int i = 0; i < 14; ++i) {
            uint4 v = rv[i];
            w[j][4 * i + 0] = v.x; w[j][4 * i + 1] = v.y;
            w[j][4 * i + 2] = v.z; w[j][4 * i + 3] = v.w;
        }
        uint4 t14 = rv[14], t15 = rv[15];
        w[j][56] = t14.x;
        wlds[0][tid * 4 + j] = t14.y;
        wlds[1][tid * 4 + j] = t14.z;
        wlds[2][tid * 4 + j] = t14.w;
        wlds[3][tid * 4 + j] = t15.x;
        wlds[4][tid * 4 + j] = t15.y;
        wlds[5][tid * 4 + j] = t15.z;
        wlds[6][tid * 4 + j] = t15.w;
    }
    hbuf[0][tid] = (u16)0;
    __syncthreads();

    const uint4* hq0 = (const uint4*)&hbuf[0][0] + 16 * kq;
    const uint4* hq1 = (const uint4*)&hbuf[1][0] + 16 * kq;
    const uint4* wldv = (const uint4*)&wlds[0][0];

    // prefetch X for t=0
    size_t idx0 = (size_t)b * 512 + tid;
    u16 xi_c = Xi[idx0], xz_c = Xz[idx0], xo_c = Xo[idx0];

    for (int t = 0; t < 2048; ++t) {
        const int cur = t & 1, nxt = cur ^ 1;
        const int tn = (t + 1) & 2047;
        const size_t idxn = ((size_t)tn * 32 + b) * 512 + tid;
        u16 xi_n = Xi[idxn], xz_n = Xz[idxn], xo_n = Xo[idxn];

        const uint4* hv = cur ? hq1 : hq0;
        float a0 = 0.f, a1 = 0.f, a2 = 0.f, a3 = 0.f;   // partials for j=0..3
        #pragma unroll
        for (int i = 0; i < 14; ++i) {
            uint4 hc = hv[i];
            a0 = fdot2(hc.x, w[0][4 * i + 0], a0);
            a1 = fdot2(hc.x, w[1][4 * i + 0], a1);
            a2 = fdot2(hc.x, w[2][4 * i + 0], a2);
            a3 = fdot2(hc.x, w[3][4 * i + 0], a3);
            a0 = fdot2(hc.y, w[0][4 * i + 1], a0);
            a1 = fdot2(hc.y, w[1][4 * i + 1], a1);
            a2 = fdot2(hc.y, w[2][4 * i + 1], a2);
            a3 = fdot2(hc.y, w[3][4 * i + 1], a3);
            a0 = fdot2(hc.z, w[0][4 * i + 2], a0);
            a1 = fdot2(hc.z, w[1][4 * i + 2], a1);
            a2 = fdot2(hc.z, w[2][4 * i + 2], a2);
            a3 = fdot2(hc.z, w[3][4 * i + 2], a3);
            a0 = fdot2(hc.w, w[0][4 * i + 3], a0);
            a1 = fdot2(hc.w, w[1][4 * i + 3], a1);
            a2 = fdot2(hc.w, w[2][4 * i + 3], a2);
            a3 = fdot2(hc.w, w[3][4 * i + 3], a3);
        }
        // tail: p=56 (VGPR), p=57..63 (LDS)
        {
            uint4 h14 = hv[14], h15 = hv[15];
            uint4 wl0 = wldv[0 * 512 + tid];
            uint4 wl1 = wldv[1 * 512 + tid];
            uint4 wl2 = wldv[2 * 512 + tid];
            uint4 wl3 = wldv[3 * 512 + tid];
            uint4 wl4 = wldv[4 * 512 + tid];
            uint4 wl5 = wldv[5 * 512 + tid];
            uint4 wl6 = wldv[6 * 512 + tid];
            a0 = fdot2(h14.x, w[0][56], a0);
            a1 = fdot2(h14.x, w[1][56], a1);
            a2 = fdot2(h14.x, w[2][56], a2);
            a3 = fdot2(h14.x, w[3][56], a3);
            a0 = fdot2(h14.y, wl0.x, a0); a1 = fdot2(h14.y, wl0.y, a1);
            a2 = fdot2(h14.y, wl0.z, a2); a3 = fdot2(h14.y, wl0.w, a3);
            a0 = fdot2(h14.z, wl1.x, a0); a1 = fdot2(h14.z, wl1.y, a1);
            a2 = fdot2(h14.z, wl1.z, a2); a3 = fdot2(h14.z, wl1.w, a3);
            a0 = fdot2(h14.w, wl2.x, a0); a1 = fdot2(h14.w, wl2.y, a1);
            a2 = fdot2(h14.w, wl2.z, a2); a3 = fdot2(h14.w, wl2.w, a3);
            a0 = fdot2(h15.x, wl3.x, a0); a1 = fdot2(h15.x, wl3.y, a1);
            a2 = fdot2(h15.x, wl3.z, a2); a3 = fdot2(h15.x, wl3.w, a3);
            a0 = fdot2(h15.y, wl4.x, a0); a1 = fdot2(h15.y, wl4.y, a1);
            a2 = fdot2(h15.y, wl4.z, a2); a3 = fdot2(h15.y, wl4.w, a3);
            a0 = fdot2(h15.z, wl5.x, a0); a1 = fdot2(h15.z, wl5.y, a1);
            a2 = fdot2(h15.z, wl5.z, a2); a3 = fdot2(h15.z, wl5.w, a3);
            a0 = fdot2(h15.w, wl6.x, a0); a1 = fdot2(h15.w, wl6.y, a1);
            a2 = fdot2(h15.w, wl6.z, a2); a3 = fdot2(h15.w, wl6.w, a3);
        }
        // quad butterfly: sum partials over the 4 kq lanes
        a0 = dpp_xor_add<0xB1>(a0); a1 = dpp_xor_add<0xB1>(a1);
        a2 = dpp_xor_add<0xB1>(a2); a3 = dpp_xor_add<0xB1>(a3);
        a0 = dpp_xor_add<0x4E>(a0); a1 = dpp_xor_add<0x4E>(a1);
        a2 = dpp_xor_add<0x4E>(a2); a3 = dpp_xor_add<0x4E>(a3);
        float v = a0;
        v = (kq == 1) ? a1 : v;
        v = (kq == 2) ? a2 : v;
        v = (kq == 3) ? a3 : v;           // v = full dot for d = tid

        const float zi = fsigmoid(h2f(xi_c) + v);
        const float z  = fsigmoid(h2f(xz_c) + v);
        const float zo = fsigmoid(h2f(xo_c) + v);
        const float hn = zo * ftanh_pos(zi * z);

        hbuf[nxt][tid] = f2h(hn);
        __syncthreads();

        xi_c = xi_n; xz_c = xz_n; xo_c = xo_n;
    }

    // epilogue: final h in hbuf[0]; out[b,:] = h @ Wy.T + by
    {
        const uint4* hv = (const uint4*)&hbuf[0][0];
        float a0 = 0.f, a1 = 0.f, a2 = 0.f, a3 = 0.f;
        #pragma unroll
        for (int i = 0; i < 64; ++i) {
            uint4 hc = hv[i];
            a0 = fdot2(hc.x, Wypk[(size_t)(4 * i + 0) * 512 + tid], a0);
            a1 = fdot2(hc.y, Wypk[(size_t)(4 * i + 1) * 512 + tid], a1);
            a2 = fdot2(hc.z, Wypk[(size_t)(4 * i + 2) * 512 + tid], a2);
            a3 = fdot2(hc.w, Wypk[(size_t)(4 * i + 3) * 512 + tid], a3);
        }
        out[(size_t)b * 512 + tid] = (a0 + a1) + (a2 + a3) + by[tid];
    }
}

// ---------------------------------------------------------------------------
extern "C" void kernel_launch(void* const* d_in, const int* in_sizes, int n_in,
                              void* d_out, int out_size, void* d_ws, size_t ws_size,
                              hipStream_t stream) {
    const float* word = (const float*)d_in[0];
    // d_in[1]=Wf, d_in[2]=bf : dead in the reference (c==0 path), unused.
    const float* Wi = (const float*)d_in[3];
    const float* bi = (const float*)d_in[4];
    const float* Wz = (const float*)d_in[5];
    const float* bz = (const float*)d_in[6];
    const float* Wo = (const float*)d_in[7];
    const float* bo = (const float*)d_in[8];
    const float* Wy = (const float*)d_in[9];
    const float* by = (const float*)d_in[10];
    float* out = (float*)d_out;

    char* ws = (char*)d_ws;
    const size_t XN = (size_t)2048 * 32 * 512 * sizeof(u16);  // 64 MB per gate array
    u16* Xi = (u16*)(ws);
    u16* Xz = (u16*)(ws + XN);
    u16* Xo = (u16*)(ws + 2 * XN);
    u32* WpkT = (u32*)(ws + 3 * XN);                  // 512 KB
    u32* Wypk = (u32*)(ws + 3 * XN + (size_t)524288); // 512 KB

    k0_pack<<<768, 256, 0, stream>>>(Wi, Wy, WpkT, Wypk);

    dim3 g1(1024, 4);
    k1_gates<<<g1, 256, 0, stream>>>(word, Wi, Wz, Wo, bi, bz, bo, Xi, Xz, Xo);

    k2_recur<<<32, 512, 0, stream>>>(Xi, Xz, Xo, WpkT, Wypk, by, out);
}